// Round 18
// baseline (554.337 us; speedup 1.0000x reference)
//
#include <hip/hip_runtime.h>
#include <cstdio>
#include <cstdint>

#define F_IN 128
#define D 256
#define EPS 1e-5f
#define BSTRIDE 6144   // fixed bucket region capacity (mean 4082, std ~64)
// N must be < 65536 for the 16-bit src/dst packing in the edge sort (N=50000).

typedef unsigned short bfu;
typedef __attribute__((ext_vector_type(8))) short bf16x8;
typedef __attribute__((ext_vector_type(4))) float f32x4;
typedef __attribute__((ext_vector_type(2))) float f32x2;

__device__ __forceinline__ float bf2f(unsigned u) {
    return __uint_as_float(u << 16);
}
__device__ __forceinline__ bfu f2bf(float f) {
    unsigned u = __float_as_uint(f);
    return (bfu)((u + 0x7fffu + ((u >> 16) & 1u)) >> 16);
}

#define GLOBAL_LOAD_LDS16(gp, lp)                                                  \
    __builtin_amdgcn_global_load_lds((const __attribute__((address_space(1))) void*)(gp), \
                                     (__attribute__((address_space(3))) void*)(lp), 16, 0, 0)

// ---------------- front end: cvt + LDS-tiled weight transposes ----------------

__global__ __launch_bounds__(256) void k_front(
    const float* __restrict__ x,
    const float* __restrict__ Wp, const float* __restrict__ Wr,
    const float* __restrict__ Wo, const float* __restrict__ Ws,
    bfu* __restrict__ xb, bfu* __restrict__ Tp, bfu* __restrict__ Tc,
    bfu* __restrict__ Ts, int cvt_blocks, int total4) {
    int b = blockIdx.x;
    int tid = threadIdx.x;
    if (b < cvt_blocks) {
        int idx = b * 256 + tid;
        if (idx >= total4) return;
        float4 v = ((const float4*)x)[idx];
        uint2 o;
        o.x = (unsigned)f2bf(v.x) | ((unsigned)f2bf(v.y) << 16);
        o.y = (unsigned)f2bf(v.z) | ((unsigned)f2bf(v.w) << 16);
        ((uint2*)xb)[idx] = o;
        return;
    }
    int t = b - cvt_blocks;          // 0..127
    int region = t >> 4;
    int tile = t & 15;
    const float* S; bfu* Dst; int K, dstStride, colOff;
    if (region == 0)      { S = Wp;                        Dst = Tp;                      K = F_IN; dstStride = F_IN; colOff = 0; }
    else if (region <= 3) { int l = region - 1; S = Wr + (size_t)l * D * D; Dst = Tc + (size_t)l * D * 512; K = D; dstStride = 512; colOff = 0; }
    else if (region <= 6) { int l = region - 4; S = Wo + (size_t)l * D * D; Dst = Tc + (size_t)l * D * 512; K = D; dstStride = 512; colOff = 256; }
    else                  { S = Ws;                        Dst = Ts;                      K = D;    dstStride = D;    colOff = 0; }
    int ktiles = K >> 6;
    if (tile >= ktiles * 4) return;
    int tr = tile >> 2, tc = tile & 3;
    __shared__ bfu ldsT[64 * 72];
    #pragma unroll
    for (int i = 0; i < 16; ++i) {
        int idx = i * 256 + tid;
        int r = idx >> 6, c = idx & 63;
        ldsT[c * 72 + r] = f2bf(S[(size_t)(tr * 64 + r) * D + tc * 64 + c]);
    }
    __syncthreads();
    int n = tid >> 2, kc = (tid & 3) * 16;
    uint4 a = *(const uint4*)&ldsT[n * 72 + kc];
    uint4 bq = *(const uint4*)&ldsT[n * 72 + kc + 8];
    bfu* dp = Dst + (size_t)(tc * 64 + n) * dstStride + colOff + tr * 64 + kc;
    *(uint4*)dp = a;
    *((uint4*)dp + 1) = bq;
}

// ---------------- edge binning: fixed bucket regions, no global scan ----------------
#define ACHUNK 4096

__global__ __launch_bounds__(256) void k_binA(const int* __restrict__ src,
                                              const int* __restrict__ dst,
                                              const float* __restrict__ ew, int E,
                                              int* __restrict__ bucket_cursor,
                                              uint2* __restrict__ s_tmp) {
    __shared__ uint2 s_rec[ACHUNK];
    __shared__ int hist[256], lstart[256], cur[256], gpos[256];
    __shared__ int wsum[4];
    int tid = threadIdx.x, lane = tid & 63, wid = tid >> 6;
    int base = blockIdx.x * ACHUNK;
    int cnt = E - base; if (cnt > ACHUNK) cnt = ACHUNK;
    hist[tid] = 0;
    __syncthreads();
    for (int i = tid; i < cnt; i += 256)
        atomicAdd(&hist[dst[base + i] >> 8], 1);
    __syncthreads();
    {
        int v = hist[tid];
        int x = v;
        #pragma unroll
        for (int off = 1; off < 64; off <<= 1) {
            int s = __shfl_up(x, off, 64);
            if (lane >= off) x += s;
        }
        if (lane == 63) wsum[wid] = x;
        __syncthreads();
        if (tid == 0) {
            int run = 0;
            #pragma unroll
            for (int wv = 0; wv < 4; ++wv) { int s = wsum[wv]; wsum[wv] = run; run += s; }
        }
        __syncthreads();
        int excl = wsum[wid] + x - v;
        lstart[tid] = excl;
        cur[tid] = excl;
    }
    __syncthreads();
    for (int i = tid; i < cnt; i += 256) {
        int d = dst[base + i];
        int r = atomicAdd(&cur[d >> 8], 1);
        uint2 rec;
        rec.x = (unsigned)src[base + i] | ((unsigned)d << 16);
        rec.y = __float_as_uint(ew[base + i]);
        s_rec[r] = rec;
    }
    __syncthreads();
    {
        int c = cur[tid] - lstart[tid];
        gpos[tid] = c ? atomicAdd(&bucket_cursor[tid], c) : 0;
    }
    __syncthreads();
    for (int i = tid; i < cnt; i += 256) {
        uint2 rec = s_rec[i];
        int bk = rec.x >> 24;
        int pos = gpos[bk] + (i - lstart[bk]);
        if (pos < BSTRIDE) s_tmp[(size_t)bk * BSTRIDE + pos] = rec;
    }
}

__global__ __launch_bounds__(256) void k_binB(const uint2* __restrict__ s_tmp,
                                              const int* __restrict__ bucket_cursor,
                                              uint2* __restrict__ s_edge,
                                              int* __restrict__ row_beg,
                                              int* __restrict__ row_end, int Nn) {
    __shared__ uint2 s_out[BSTRIDE];
    __shared__ int hist[256], excl[256], cur[256];
    __shared__ int wsum[4];
    int tid = threadIdx.x, lane = tid & 63, wid = tid >> 6;
    int b = blockIdx.x;
    int base = b * BSTRIDE;
    int cnt = bucket_cursor[b];
    if (cnt > BSTRIDE) cnt = BSTRIDE;
    hist[tid] = 0;
    __syncthreads();
    for (int i = tid; i < cnt; i += 256)
        atomicAdd(&hist[(s_tmp[base + i].x >> 16) & 255], 1);
    __syncthreads();
    {
        int v = hist[tid];
        int x = v;
        #pragma unroll
        for (int off = 1; off < 64; off <<= 1) {
            int s = __shfl_up(x, off, 64);
            if (lane >= off) x += s;
        }
        if (lane == 63) wsum[wid] = x;
        __syncthreads();
        if (tid == 0) {
            int run = 0;
            #pragma unroll
            for (int wv = 0; wv < 4; ++wv) { int s = wsum[wv]; wsum[wv] = run; run += s; }
        }
        __syncthreads();
        int e = wsum[wid] + x - v;
        excl[tid] = e;
        cur[tid] = e;
        int node = (b << 8) + tid;
        if (node < Nn) {
            row_beg[node] = base + e;
            row_end[node] = base + e + hist[tid];
        }
    }
    __syncthreads();
    for (int i = tid; i < cnt; i += 256) {
        uint2 rec = s_tmp[base + i];
        int r = atomicAdd(&cur[(rec.x >> 16) & 255], 1);
        uint2 o; o.x = rec.x & 0xffffu; o.y = rec.y;
        s_out[r] = o;
    }
    __syncthreads();
    for (int i = tid; i < cnt; i += 256)
        s_edge[base + i] = s_out[i];
}

// ---------------- aggregation (bf16, layers 1-2): uint4 gathers, lane-halves ----------------

__global__ __launch_bounds__(256) void k_agg(const bfu* __restrict__ h,
                                             const int* __restrict__ row_beg,
                                             const int* __restrict__ row_end,
                                             const uint2* __restrict__ s_edge,
                                             bfu* __restrict__ agg, int Nn) {
    int node = (int)((blockIdx.x * blockDim.x + threadIdx.x) >> 6);
    int lane = threadIdx.x & 63;
    if (node >= Nn) return;
    int half = lane >> 5;
    int l2 = lane & 31;
    int beg = row_beg[node], end = row_end[node];
    const uint4* hv = (const uint4*)h;
    float acc[8];
    #pragma unroll
    for (int k = 0; k < 8; ++k) acc[k] = 0.f;
    int e = beg;
    for (; e + 7 < end; e += 8) {
        uint2 p[4];
        #pragma unroll
        for (int j = 0; j < 4; ++j) p[j] = s_edge[e + 2 * j + half];
        uint4 v[4];
        #pragma unroll
        for (int j = 0; j < 4; ++j) v[j] = hv[(size_t)p[j].x * 32 + l2];
        #pragma unroll
        for (int j = 0; j < 4; ++j) {
            float w = __uint_as_float(p[j].y);
            unsigned u[4] = {v[j].x, v[j].y, v[j].z, v[j].w};
            #pragma unroll
            for (int k = 0; k < 4; ++k) {
                acc[2 * k]     += w * bf2f(u[k] & 0xffffu);
                acc[2 * k + 1] += w * bf2f(u[k] >> 16);
            }
        }
    }
    for (; e + 1 < end; e += 2) {
        uint2 p = s_edge[e + half];
        uint4 v = hv[(size_t)p.x * 32 + l2];
        float w = __uint_as_float(p.y);
        unsigned u[4] = {v.x, v.y, v.z, v.w};
        #pragma unroll
        for (int k = 0; k < 4; ++k) {
            acc[2 * k]     += w * bf2f(u[k] & 0xffffu);
            acc[2 * k + 1] += w * bf2f(u[k] >> 16);
        }
    }
    if (half == 0 && e < end) {
        uint2 p = s_edge[e];
        uint4 v = hv[(size_t)p.x * 32 + l2];
        float w = __uint_as_float(p.y);
        unsigned u[4] = {v.x, v.y, v.z, v.w};
        #pragma unroll
        for (int k = 0; k < 4; ++k) {
            acc[2 * k]     += w * bf2f(u[k] & 0xffffu);
            acc[2 * k + 1] += w * bf2f(u[k] >> 16);
        }
    }
    #pragma unroll
    for (int k = 0; k < 8; ++k)
        acc[k] += __shfl_down(acc[k], 32, 64);
    if (half == 0) {
        uint4 o;
        o.x = (unsigned)f2bf(acc[0]) | ((unsigned)f2bf(acc[1]) << 16);
        o.y = (unsigned)f2bf(acc[2]) | ((unsigned)f2bf(acc[3]) << 16);
        o.z = (unsigned)f2bf(acc[4]) | ((unsigned)f2bf(acc[5]) << 16);
        o.w = (unsigned)f2bf(acc[6]) | ((unsigned)f2bf(acc[7]) << 16);
        ((uint4*)agg)[(size_t)node * 32 + l2] = o;
    }
}

// ---------------- aggregation (fp8, layer 0): 16 lanes/edge, 4 edges/instruction ----------
// h8 row = 256 B = 16 uint4; lane = slot*16 + l16, slot handles edge e+slot.
// One gather instruction services 4 edges -> 2x edges-in-flight vs bf16.

__device__ __forceinline__ void acc16_fp8(float* acc, uint4 v, float w) {
    unsigned u[4] = {v.x, v.y, v.z, v.w};
    #pragma unroll
    for (int q = 0; q < 4; ++q) {
        f32x2 lo = __builtin_amdgcn_cvt_pk_f32_fp8(u[q], false);
        f32x2 hi = __builtin_amdgcn_cvt_pk_f32_fp8(u[q], true);
        acc[4 * q]     += w * lo.x;
        acc[4 * q + 1] += w * lo.y;
        acc[4 * q + 2] += w * hi.x;
        acc[4 * q + 3] += w * hi.y;
    }
}

__global__ __launch_bounds__(256) void k_agg_fp8(const unsigned* __restrict__ h8,
                                                 const int* __restrict__ row_beg,
                                                 const int* __restrict__ row_end,
                                                 const uint2* __restrict__ s_edge,
                                                 bfu* __restrict__ agg, int Nn) {
    int node = (int)((blockIdx.x * blockDim.x + threadIdx.x) >> 6);
    int lane = threadIdx.x & 63;
    if (node >= Nn) return;
    int slot = lane >> 4;     // edge slot 0..3
    int l16 = lane & 15;      // 16 B chunk within the 256 B row
    int beg = row_beg[node], end = row_end[node];
    const uint4* hv = (const uint4*)h8;   // row = 16 uint4
    float acc[16];
    #pragma unroll
    for (int k = 0; k < 16; ++k) acc[k] = 0.f;
    int e = beg;
    for (; e + 15 < end; e += 16) {       // 16 edges in flight (4 loads x 4 slots)
        uint2 p[4];
        #pragma unroll
        for (int j = 0; j < 4; ++j) p[j] = s_edge[e + 4 * j + slot];
        uint4 v[4];
        #pragma unroll
        for (int j = 0; j < 4; ++j) v[j] = hv[(size_t)p[j].x * 16 + l16];
        #pragma unroll
        for (int j = 0; j < 4; ++j)
            acc16_fp8(acc, v[j], __uint_as_float(p[j].y));
    }
    for (; e + 3 < end; e += 4) {
        uint2 p = s_edge[e + slot];
        uint4 v = hv[(size_t)p.x * 16 + l16];
        acc16_fp8(acc, v, __uint_as_float(p.y));
    }
    if (e + slot < end) {
        uint2 p = s_edge[e + slot];
        uint4 v = hv[(size_t)p.x * 16 + l16];
        acc16_fp8(acc, v, __uint_as_float(p.y));
    }
    // reduce across the 4 edge slots (lanes differing in bits 4-5)
    #pragma unroll
    for (int k = 0; k < 16; ++k) {
        acc[k] += __shfl_xor(acc[k], 16, 64);
        acc[k] += __shfl_xor(acc[k], 32, 64);
    }
    if (slot == 0) {
        // lane l16 owns features [l16*16, l16*16+16) = 32 B of bf16
        uint4 o0, o1;
        o0.x = (unsigned)f2bf(acc[0])  | ((unsigned)f2bf(acc[1])  << 16);
        o0.y = (unsigned)f2bf(acc[2])  | ((unsigned)f2bf(acc[3])  << 16);
        o0.z = (unsigned)f2bf(acc[4])  | ((unsigned)f2bf(acc[5])  << 16);
        o0.w = (unsigned)f2bf(acc[6])  | ((unsigned)f2bf(acc[7])  << 16);
        o1.x = (unsigned)f2bf(acc[8])  | ((unsigned)f2bf(acc[9])  << 16);
        o1.y = (unsigned)f2bf(acc[10]) | ((unsigned)f2bf(acc[11]) << 16);
        o1.z = (unsigned)f2bf(acc[12]) | ((unsigned)f2bf(acc[13]) << 16);
        o1.w = (unsigned)f2bf(acc[14]) | ((unsigned)f2bf(acc[15]) << 16);
        uint4* gp = (uint4*)agg + (size_t)node * 32 + l16 * 2;
        gp[0] = o0;
        gp[1] = o1;
    }
}

// ---------------- bf16 MFMA GEMM: 64x64 tile, BK=64, XOR-swizzled LDS ----------------

__global__ __launch_bounds__(256) void gemm_mfma(
    const bfu* __restrict__ A1, int lda1, int K1,
    const bfu* __restrict__ A2, int lda2, int K2,
    const bfu* __restrict__ Wc, const float* __restrict__ bias,
    bfu* __restrict__ out, float* __restrict__ stats, int M) {
    __shared__ bfu lds[8192];
    __shared__ float sstat[128];
    bfu* As = lds;
    bfu* Bs = lds + 4096;
    bfu* Ct = lds;
    const int KT = K1 + K2;
    int tid = threadIdx.x;
    int lane = tid & 63;
    int w = tid >> 6;
    int wm = (w >> 1) * 32;
    int wn = (w & 1) * 32;
    int bid = blockIdx.x;
    int xcd = bid & 7;
    int slot = bid >> 3;
    int row0 = ((slot >> 2) * 8 + xcd) * 64;
    int col0 = (slot & 3) * 64;

    if (tid < 128) sstat[tid] = 0.f;

    f32x4 acc[2][2];
    #pragma unroll
    for (int i = 0; i < 2; ++i)
        #pragma unroll
        for (int j = 0; j < 2; ++j) acc[i][j] = (f32x4)(0.f);

    int sr8 = lane >> 3;
    int sslot = lane & 7;
    int rsel = lane & 15;
    int kg = lane >> 4;

    for (int k0 = 0; k0 < KT; k0 += 64) {
        const bfu* A; int lda, kk;
        if (k0 < K1) { A = A1; lda = lda1; kk = k0; }
        else         { A = A2; lda = lda2; kk = k0 - K1; }
        __syncthreads();
        #pragma unroll
        for (int t = 0; t < 2; ++t) {
            int r = w * 16 + t * 8 + sr8;
            int g = (sslot - r) & 7;
            GLOBAL_LOAD_LDS16(A + (size_t)(row0 + r) * lda + kk + g * 8,
                              As + (w * 16 + t * 8) * 64);
        }
        #pragma unroll
        for (int t = 0; t < 2; ++t) {
            int r = w * 16 + t * 8 + sr8;
            int g = (sslot - r) & 7;
            GLOBAL_LOAD_LDS16(Wc + (size_t)(col0 + r) * KT + k0 + g * 8,
                              Bs + (w * 16 + t * 8) * 64);
        }
        __syncthreads();

        bf16x8 af[2][2], bfr[2][2];
        #pragma unroll
        for (int ks = 0; ks < 2; ++ks) {
            #pragma unroll
            for (int i = 0; i < 2; ++i) {
                int rr = wm + i * 16 + rsel;
                int cc = ks * 4 + kg;
                af[ks][i] = *(const bf16x8*)&As[rr * 64 + (((cc + rr) & 7) << 3)];
            }
            #pragma unroll
            for (int j = 0; j < 2; ++j) {
                int nn = wn + j * 16 + rsel;
                int cc = ks * 4 + kg;
                bfr[ks][j] = *(const bf16x8*)&Bs[nn * 64 + (((cc + nn) & 7) << 3)];
            }
        }
        #pragma unroll
        for (int ks = 0; ks < 2; ++ks)
            #pragma unroll
            for (int i = 0; i < 2; ++i)
                #pragma unroll
                for (int j = 0; j < 2; ++j)
                    acc[i][j] = __builtin_amdgcn_mfma_f32_16x16x32_bf16(
                        af[ks][i], bfr[ks][j], acc[i][j], 0, 0, 0);
    }

    __syncthreads();

    int lgrp = lane >> 4;
    #pragma unroll
    for (int j = 0; j < 2; ++j) {
        int ccol = wn + j * 16 + rsel;
        float bv = bias[col0 + ccol];
        float s = 0.f, s2 = 0.f;
        #pragma unroll
        for (int i = 0; i < 2; ++i) {
            int rrb = wm + i * 16 + lgrp * 4;
            #pragma unroll
            for (int r = 0; r < 4; ++r) {
                int rr = rrb + r;
                float v = acc[i][j][r] + bv;
                Ct[rr * 72 + ccol] = f2bf(v);
                if (row0 + rr < M) { s += v; s2 += v * v; }
            }
        }
        s  += __shfl_xor(s, 16, 64);  s  += __shfl_xor(s, 32, 64);
        s2 += __shfl_xor(s2, 16, 64); s2 += __shfl_xor(s2, 32, 64);
        if (lgrp == 0) {
            atomicAdd(&sstat[ccol], s);
            atomicAdd(&sstat[64 + ccol], s2);
        }
    }
    __syncthreads();

    if (tid < 128) {
        int c = tid & 63;
        float v = sstat[tid];
        if (tid < 64) atomicAdd(&stats[col0 + c], v);
        else          atomicAdd(&stats[D + col0 + c], v);
    }

    int r = tid >> 2, cq = (tid & 3) * 16;
    if (row0 + r < M) {
        uint4 a = *(const uint4*)&Ct[r * 72 + cq];
        uint4 b = *(const uint4*)&Ct[r * 72 + cq + 8];
        uint4* gp = (uint4*)&out[(size_t)(row0 + r) * D + col0 + cq];
        gp[0] = a;
        gp[1] = b;
    }
}

// ---------------- BN apply: bf16 in -> bf16 h (+ optional fp8 h8) ----------------

__global__ __launch_bounds__(256) void bn_prelu_bf16(const bfu* __restrict__ hf,
                                                     const float* __restrict__ stats,
                                                     const float* __restrict__ g,
                                                     const float* __restrict__ be,
                                                     const float* __restrict__ a_ptr,
                                                     bfu* __restrict__ hb,
                                                     unsigned* __restrict__ h8,
                                                     int total4, int Nrows) {
    int idx = blockIdx.x * 256 + threadIdx.x;
    if (idx >= total4) return;
    float a = a_ptr[0];
    float inv = 1.0f / (float)Nrows;
    int c4 = (idx & 63) * 4;
    uint2 v = ((const uint2*)hf)[idx];
    float vin[4] = {bf2f(v.x & 0xffffu), bf2f(v.x >> 16),
                    bf2f(v.y & 0xffffu), bf2f(v.y >> 16)};
    float uo[4];
    bfu o[4];
    #pragma unroll
    for (int t = 0; t < 4; ++t) {
        int c = c4 + t;
        float m = stats[c] * inv;
        float var = stats[D + c] * inv - m * m;
        float sc = rsqrtf(var + EPS) * g[c];
        float sh = be[c] - m * sc;
        float u = vin[t] * sc + sh;
        u = u >= 0.f ? u : a * u;
        uo[t] = u;
        o[t] = f2bf(u);
    }
    uint2 ov;
    ov.x = (unsigned)o[0] | ((unsigned)o[1] << 16);
    ov.y = (unsigned)o[2] | ((unsigned)o[3] << 16);
    ((uint2*)hb)[idx] = ov;
    if (h8) {
        unsigned p8 = 0;
        p8 = __builtin_amdgcn_cvt_pk_fp8_f32(uo[0], uo[1], p8, false);
        p8 = __builtin_amdgcn_cvt_pk_fp8_f32(uo[2], uo[3], p8, true);
        h8[idx] = p8;
    }
}

// ---------------- fused post-BN + PReLU + head dot ----------------

__global__ __launch_bounds__(256) void k_final_fused(
    const float* __restrict__ x, const bfu* __restrict__ outf,
    const float* __restrict__ stats, const float* __restrict__ g,
    const float* __restrict__ be, const float* __restrict__ a_ptr,
    const float* __restrict__ Wf, const float* __restrict__ bf_,
    float* __restrict__ z, int Nn, int Nrows) {
    int node = (int)((blockIdx.x * blockDim.x + threadIdx.x) >> 6);
    int lane = threadIdx.x & 63;
    if (node >= Nn) return;
    float a = a_ptr[0];
    float inv = 1.0f / (float)Nrows;
    float s = x[(size_t)node * F_IN + lane] * Wf[lane]
            + x[(size_t)node * F_IN + 64 + lane] * Wf[64 + lane];
    uint2 v  = ((const uint2*)outf)[(size_t)node * 64 + lane];
    float4 wv = ((const float4*)(Wf + F_IN))[lane];
    float4 st1 = ((const float4*)stats)[lane];
    float4 st2 = ((const float4*)(stats + D))[lane];
    float4 gv = ((const float4*)g)[lane];
    float4 bev = ((const float4*)be)[lane];
    float vin[4] = {bf2f(v.x & 0xffffu), bf2f(v.x >> 16),
                    bf2f(v.y & 0xffffu), bf2f(v.y >> 16)};
    float m1[4] = {st1.x, st1.y, st1.z, st1.w};
    float m2[4] = {st2.x, st2.y, st2.z, st2.w};
    float gg[4] = {gv.x, gv.y, gv.z, gv.w};
    float bb[4] = {bev.x, bev.y, bev.z, bev.w};
    float ww[4] = {wv.x, wv.y, wv.z, wv.w};
    #pragma unroll
    for (int t = 0; t < 4; ++t) {
        float m = m1[t] * inv;
        float var = m2[t] * inv - m * m;
        float sc = rsqrtf(var + EPS) * gg[t];
        float sh = bb[t] - m * sc;
        float u = vin[t] * sc + sh;
        u = u >= 0.f ? u : a * u;
        s += u * ww[t];
    }
    #pragma unroll
    for (int off = 32; off; off >>= 1) s += __shfl_down(s, off, 64);
    if (lane == 0) z[node] = s + bf_[0];
}

__global__ __launch_bounds__(256) void k_zstats(const float* __restrict__ z,
                                                float* __restrict__ zs, int n) {
    float s = 0.f, s2 = 0.f;
    for (int i = blockIdx.x * blockDim.x + threadIdx.x; i < n; i += gridDim.x * blockDim.x) {
        float v = z[i];
        s += v; s2 += v * v;
    }
    #pragma unroll
    for (int off = 32; off; off >>= 1) {
        s += __shfl_down(s, off, 64);
        s2 += __shfl_down(s2, off, 64);
    }
    __shared__ float ws[4], ws2[4];
    int lane = threadIdx.x & 63, wid = threadIdx.x >> 6;
    if (lane == 0) { ws[wid] = s; ws2[wid] = s2; }
    __syncthreads();
    if (threadIdx.x == 0) {
        atomicAdd(&zs[0], ws[0] + ws[1] + ws[2] + ws[3]);
        atomicAdd(&zs[1], ws2[0] + ws2[1] + ws2[2] + ws2[3]);
    }
}

__global__ __launch_bounds__(256) void k_logsm(const float* __restrict__ z,
                                               const float* __restrict__ zs,
                                               const float* __restrict__ g,
                                               const float* __restrict__ be,
                                               const float* __restrict__ a_ptr,
                                               float* __restrict__ out, int C, int Ntot) {
    __shared__ float red[4], red2[4];
    int t = threadIdx.x;
    int lane = t & 63, wid = t >> 6;
    float mean = zs[0] / (float)Ntot;
    float var = zs[1] / (float)Ntot - mean * mean;
    float sc = rsqrtf(var + EPS) * g[0];
    float sh = be[0] - mean * sc;
    float a = a_ptr[0];
    const float* zg = z + (size_t)blockIdx.x * C;
    float vals[4];
    int cnt = 0;
    float mx = -3.4e38f;
    for (int i = t; i < C; i += 256) {
        float u = zg[i] * sc + sh;
        u = u >= 0.f ? u : a * u;
        vals[cnt++] = u;
        mx = fmaxf(mx, u);
    }
    #pragma unroll
    for (int off = 32; off; off >>= 1) mx = fmaxf(mx, __shfl_down(mx, off, 64));
    if (lane == 0) red[wid] = mx;
    __syncthreads();
    float M4 = fmaxf(fmaxf(red[0], red[1]), fmaxf(red[2], red[3]));
    float se = 0.f;
    for (int j = 0; j < cnt; ++j) se += expf(vals[j] - M4);
    #pragma unroll
    for (int off = 32; off; off >>= 1) se += __shfl_down(se, off, 64);
    if (lane == 0) red2[wid] = se;
    __syncthreads();
    float S4 = red2[0] + red2[1] + red2[2] + red2[3];
    float lse = logf(S4) + M4;
    cnt = 0;
    for (int i = t; i < C; i += 256) out[(size_t)blockIdx.x * C + i] = vals[cnt++] - lse;
}

// ---------------- launch ----------------

extern "C" void kernel_launch(void* const* d_in, const int* in_sizes, int n_in,
                              void* d_out, int out_size, void* d_ws, size_t ws_size,
                              hipStream_t stream) {
    const float* x      = (const float*)d_in[0];
    const int*   eidx   = (const int*)d_in[1];
    const float* e_w    = (const float*)d_in[2];
    const float* W_pre  = (const float*)d_in[4];
    const float* b_pre  = (const float*)d_in[5];
    const float* g_pre  = (const float*)d_in[6];
    const float* be_pre = (const float*)d_in[7];
    const float* a_pre  = (const float*)d_in[8];
    const float* W_rel  = (const float*)d_in[9];
    const float* b_rel  = (const float*)d_in[10];
    const float* W_root = (const float*)d_in[11];
    const float* g_conv = (const float*)d_in[12];
    const float* be_conv= (const float*)d_in[13];
    const float* a_conv = (const float*)d_in[14];
    const float* W_post = (const float*)d_in[15];
    const float* b_post = (const float*)d_in[16];
    const float* g_post = (const float*)d_in[17];
    const float* be_post= (const float*)d_in[18];
    const float* a_post = (const float*)d_in[19];
    const float* W_fin  = (const float*)d_in[20];
    const float* b_fin  = (const float*)d_in[21];
    const float* g_fin  = (const float*)d_in[22];
    const float* be_fin = (const float*)d_in[23];
    const float* a_fin  = (const float*)d_in[24];

    const int N = in_sizes[0] / F_IN;   // 50000
    const int E = in_sizes[2];          // 800000
    const int L = in_sizes[14];         // 3
    const int Npad = ((N + 511) / 512) * 512;   // 50176
    const int NB = (N + 255) >> 8;      // node buckets (196)
    const int* e_src = eidx;
    const int* e_dst = eidx + E;

    uint8_t* wsp = (uint8_t*)d_ws;
    size_t used = 0;
    auto alloc = [&](size_t bytes) -> void* {
        void* p = wsp + used;
        used += (bytes + 255) & ~(size_t)255;
        return p;
    };
    bfu*   xb       = (bfu*)alloc((size_t)Npad * F_IN * 2);
    bfu*   hb0      = (bfu*)alloc((size_t)Npad * D * 2);
    bfu*   hb1      = (bfu*)alloc((size_t)Npad * D * 2);
    unsigned* h8    = (unsigned*)alloc((size_t)Npad * D);
    bfu*   aggb     = (bfu*)alloc((size_t)Npad * D * 2);
    bfu*   outb     = (bfu*)alloc((size_t)Npad * D * 2);
    bfu*   Wt_pre   = (bfu*)alloc((size_t)D * F_IN * 2);
    bfu*   Wt_conv  = (bfu*)alloc((size_t)L * D * 512 * 2);
    bfu*   Wt_post  = (bfu*)alloc((size_t)D * D * 2);
    float* z        = (float*)alloc((size_t)N * 4);
    float* statsall = (float*)alloc((size_t)(5 * 2 * D + 2) * 4);
    int*   bucket_cursor = (int*)alloc((size_t)NB * 4);
    int*   row_beg  = (int*)alloc((size_t)N * 4);
    int*   row_end  = (int*)alloc((size_t)N * 4);
    uint2* s_tmp    = (uint2*)alloc((size_t)NB * BSTRIDE * 8);
    uint2* s_edge   = (uint2*)alloc((size_t)NB * BSTRIDE * 8);
    if (used > ws_size) {
        fprintf(stderr, "kernel_launch: ws too small (%zu > %zu)\n", used, ws_size);
        return;
    }
    float* st_pre  = statsall;
    float* st_post = statsall + 4 * 2 * D;
    float* zstats  = statsall + 5 * 2 * D;

    hipMemsetAsync(bucket_cursor, 0, (size_t)NB * 4, stream);
    hipMemsetAsync(statsall, 0, (size_t)(5 * 2 * D + 2) * 4, stream);

    // front end: cvt + LDS-tiled transposes (one launch)
    const int total4 = N * (F_IN / 4);
    const int CVT_BLOCKS = (total4 + 255) / 256;
    k_front<<<CVT_BLOCKS + 128, 256, 0, stream>>>(
        x, W_pre, W_rel, W_root, W_post,
        xb, Wt_pre, Wt_conv, Wt_post, CVT_BLOCKS, total4);

    // edge binning into fixed bucket regions (no global scan)
    k_binA<<<(E + ACHUNK - 1) / ACHUNK, 256, 0, stream>>>(e_src, e_dst, e_w, E,
                                                          bucket_cursor, s_tmp);
    k_binB<<<NB, 256, 0, stream>>>(s_tmp, bucket_cursor, s_edge, row_beg, row_end, N);

    const int gemm_grid = (Npad / 64) * 4;
    const int bn_blocks = (N * (D / 4) + 255) / 256;
    const int wave_blocks = (N + 3) / 4;

    // preprocess (BN dual-writes bf16 + fp8 shadow for layer-0 gather)
    gemm_mfma<<<gemm_grid, 256, 0, stream>>>(xb, F_IN, F_IN, nullptr, 0, 0,
                                             Wt_pre, b_pre, outb, st_pre, N);
    bn_prelu_bf16<<<bn_blocks, 256, 0, stream>>>(outb, st_pre, g_pre, be_pre, a_pre,
                                                 hb0, h8, N * (D / 4), N);

    bfu* hc = hb0;
    bfu* hn = hb1;
    for (int l = 0; l < L; ++l) {
        float* st = statsall + (1 + l) * 2 * D;
        if (l == 0)
            k_agg_fp8<<<wave_blocks, 256, 0, stream>>>(h8, row_beg, row_end, s_edge,
                                                       aggb, N);
        else
            k_agg<<<wave_blocks, 256, 0, stream>>>(hc, row_beg, row_end, s_edge,
                                                   aggb, N);
        gemm_mfma<<<gemm_grid, 256, 0, stream>>>(aggb, D, D, hc, D, D,
                                                 Wt_conv + (size_t)l * D * 512,
                                                 b_rel + (size_t)l * D, outb, st, N);
        bn_prelu_bf16<<<bn_blocks, 256, 0, stream>>>(outb, st, g_conv + (size_t)l * D,
                                                     be_conv + (size_t)l * D, a_conv + l,
                                                     hn, nullptr, N * (D / 4), N);
        bfu* tmp = hc; hc = hn; hn = tmp;
    }

    // postprocess gemm (stats fused) -> fused BN+PReLU+head dot
    gemm_mfma<<<gemm_grid, 256, 0, stream>>>(hc, D, D, nullptr, 0, 0,
                                             Wt_post, b_post, outb, st_post, N);
    k_final_fused<<<wave_blocks, 256, 0, stream>>>(x, outb, st_post, g_post, be_post,
                                                   a_post, W_fin, b_fin, z, N, N);
    k_zstats<<<64, 256, 0, stream>>>(z, zstats, N);
    k_logsm<<<N / 1000, 256, 0, stream>>>(z, zstats, g_fin, be_fin, a_fin,
                                          (float*)d_out, 1000, N);
}

// Round 19
// 531.981 us; speedup vs baseline: 1.0420x; 1.0420x over previous
//
#include <hip/hip_runtime.h>
#include <cstdio>
#include <cstdint>

#define F_IN 128
#define D 256
#define EPS 1e-5f
#define BSTRIDE 6144   // fixed bucket region capacity (mean 4082, std ~64)
// N must be < 65536 for the 16-bit src/dst packing in the edge sort (N=50000).

typedef unsigned short bfu;
typedef __attribute__((ext_vector_type(8))) short bf16x8;
typedef __attribute__((ext_vector_type(4))) float f32x4;
typedef __attribute__((ext_vector_type(2))) float f32x2;

__device__ __forceinline__ float bf2f(unsigned u) {
    return __uint_as_float(u << 16);
}
__device__ __forceinline__ bfu f2bf(float f) {
    unsigned u = __float_as_uint(f);
    return (bfu)((u + 0x7fffu + ((u >> 16) & 1u)) >> 16);
}

#define GLOBAL_LOAD_LDS16(gp, lp)                                                  \
    __builtin_amdgcn_global_load_lds((const __attribute__((address_space(1))) void*)(gp), \
                                     (__attribute__((address_space(3))) void*)(lp), 16, 0, 0)

// ---------------- front end: cvt + LDS-tiled weight transposes ----------------

__global__ __launch_bounds__(256) void k_front(
    const float* __restrict__ x,
    const float* __restrict__ Wp, const float* __restrict__ Wr,
    const float* __restrict__ Wo, const float* __restrict__ Ws,
    bfu* __restrict__ xb, bfu* __restrict__ Tp, bfu* __restrict__ Tc,
    bfu* __restrict__ Ts, int cvt_blocks, int total4) {
    int b = blockIdx.x;
    int tid = threadIdx.x;
    if (b < cvt_blocks) {
        int idx = b * 256 + tid;
        if (idx >= total4) return;
        float4 v = ((const float4*)x)[idx];
        uint2 o;
        o.x = (unsigned)f2bf(v.x) | ((unsigned)f2bf(v.y) << 16);
        o.y = (unsigned)f2bf(v.z) | ((unsigned)f2bf(v.w) << 16);
        ((uint2*)xb)[idx] = o;
        return;
    }
    int t = b - cvt_blocks;          // 0..127
    int region = t >> 4;
    int tile = t & 15;
    const float* S; bfu* Dst; int K, dstStride, colOff;
    if (region == 0)      { S = Wp;                        Dst = Tp;                      K = F_IN; dstStride = F_IN; colOff = 0; }
    else if (region <= 3) { int l = region - 1; S = Wr + (size_t)l * D * D; Dst = Tc + (size_t)l * D * 512; K = D; dstStride = 512; colOff = 0; }
    else if (region <= 6) { int l = region - 4; S = Wo + (size_t)l * D * D; Dst = Tc + (size_t)l * D * 512; K = D; dstStride = 512; colOff = 256; }
    else                  { S = Ws;                        Dst = Ts;                      K = D;    dstStride = D;    colOff = 0; }
    int ktiles = K >> 6;
    if (tile >= ktiles * 4) return;
    int tr = tile >> 2, tc = tile & 3;
    __shared__ bfu ldsT[64 * 72];
    #pragma unroll
    for (int i = 0; i < 16; ++i) {
        int idx = i * 256 + tid;
        int r = idx >> 6, c = idx & 63;
        ldsT[c * 72 + r] = f2bf(S[(size_t)(tr * 64 + r) * D + tc * 64 + c]);
    }
    __syncthreads();
    int n = tid >> 2, kc = (tid & 3) * 16;
    uint4 a = *(const uint4*)&ldsT[n * 72 + kc];
    uint4 bq = *(const uint4*)&ldsT[n * 72 + kc + 8];
    bfu* dp = Dst + (size_t)(tc * 64 + n) * dstStride + colOff + tr * 64 + kc;
    *(uint4*)dp = a;
    *((uint4*)dp + 1) = bq;
}

// ---------------- edge binning: fixed bucket regions, no global scan ----------------
#define ACHUNK 4096

__global__ __launch_bounds__(256) void k_binA(const int* __restrict__ src,
                                              const int* __restrict__ dst,
                                              const float* __restrict__ ew, int E,
                                              int* __restrict__ bucket_cursor,
                                              uint2* __restrict__ s_tmp) {
    __shared__ uint2 s_rec[ACHUNK];
    __shared__ int hist[256], lstart[256], cur[256], gpos[256];
    __shared__ int wsum[4];
    int tid = threadIdx.x, lane = tid & 63, wid = tid >> 6;
    int base = blockIdx.x * ACHUNK;
    int cnt = E - base; if (cnt > ACHUNK) cnt = ACHUNK;
    hist[tid] = 0;
    __syncthreads();
    for (int i = tid; i < cnt; i += 256)
        atomicAdd(&hist[dst[base + i] >> 8], 1);
    __syncthreads();
    {
        int v = hist[tid];
        int x = v;
        #pragma unroll
        for (int off = 1; off < 64; off <<= 1) {
            int s = __shfl_up(x, off, 64);
            if (lane >= off) x += s;
        }
        if (lane == 63) wsum[wid] = x;
        __syncthreads();
        if (tid == 0) {
            int run = 0;
            #pragma unroll
            for (int wv = 0; wv < 4; ++wv) { int s = wsum[wv]; wsum[wv] = run; run += s; }
        }
        __syncthreads();
        int excl = wsum[wid] + x - v;
        lstart[tid] = excl;
        cur[tid] = excl;
    }
    __syncthreads();
    for (int i = tid; i < cnt; i += 256) {
        int d = dst[base + i];
        int r = atomicAdd(&cur[d >> 8], 1);
        uint2 rec;
        rec.x = (unsigned)src[base + i] | ((unsigned)d << 16);
        rec.y = __float_as_uint(ew[base + i]);
        s_rec[r] = rec;
    }
    __syncthreads();
    {
        int c = cur[tid] - lstart[tid];
        gpos[tid] = c ? atomicAdd(&bucket_cursor[tid], c) : 0;
    }
    __syncthreads();
    for (int i = tid; i < cnt; i += 256) {
        uint2 rec = s_rec[i];
        int bk = rec.x >> 24;
        int pos = gpos[bk] + (i - lstart[bk]);
        if (pos < BSTRIDE) s_tmp[(size_t)bk * BSTRIDE + pos] = rec;
    }
}

__global__ __launch_bounds__(256) void k_binB(const uint2* __restrict__ s_tmp,
                                              const int* __restrict__ bucket_cursor,
                                              uint2* __restrict__ s_edge,
                                              int* __restrict__ row_beg,
                                              int* __restrict__ row_end, int Nn) {
    __shared__ uint2 s_out[BSTRIDE];
    __shared__ int hist[256], excl[256], cur[256];
    __shared__ int wsum[4];
    int tid = threadIdx.x, lane = tid & 63, wid = tid >> 6;
    int b = blockIdx.x;
    int base = b * BSTRIDE;
    int cnt = bucket_cursor[b];
    if (cnt > BSTRIDE) cnt = BSTRIDE;
    hist[tid] = 0;
    __syncthreads();
    for (int i = tid; i < cnt; i += 256)
        atomicAdd(&hist[(s_tmp[base + i].x >> 16) & 255], 1);
    __syncthreads();
    {
        int v = hist[tid];
        int x = v;
        #pragma unroll
        for (int off = 1; off < 64; off <<= 1) {
            int s = __shfl_up(x, off, 64);
            if (lane >= off) x += s;
        }
        if (lane == 63) wsum[wid] = x;
        __syncthreads();
        if (tid == 0) {
            int run = 0;
            #pragma unroll
            for (int wv = 0; wv < 4; ++wv) { int s = wsum[wv]; wsum[wv] = run; run += s; }
        }
        __syncthreads();
        int e = wsum[wid] + x - v;
        excl[tid] = e;
        cur[tid] = e;
        int node = (b << 8) + tid;
        if (node < Nn) {
            row_beg[node] = base + e;
            row_end[node] = base + e + hist[tid];
        }
    }
    __syncthreads();
    for (int i = tid; i < cnt; i += 256) {
        uint2 rec = s_tmp[base + i];
        int r = atomicAdd(&cur[(rec.x >> 16) & 255], 1);
        uint2 o; o.x = rec.x & 0xffffu; o.y = rec.y;
        s_out[r] = o;
    }
    __syncthreads();
    for (int i = tid; i < cnt; i += 256)
        s_edge[base + i] = s_out[i];
}

// ---------------- aggregation (bf16, layers 1-2): uint4 gathers, lane-halves ----------------

__global__ __launch_bounds__(256) void k_agg(const bfu* __restrict__ h,
                                             const int* __restrict__ row_beg,
                                             const int* __restrict__ row_end,
                                             const uint2* __restrict__ s_edge,
                                             bfu* __restrict__ agg, int Nn) {
    int node = (int)((blockIdx.x * blockDim.x + threadIdx.x) >> 6);
    int lane = threadIdx.x & 63;
    if (node >= Nn) return;
    int half = lane >> 5;
    int l2 = lane & 31;
    int beg = row_beg[node], end = row_end[node];
    const uint4* hv = (const uint4*)h;
    float acc[8];
    #pragma unroll
    for (int k = 0; k < 8; ++k) acc[k] = 0.f;
    int e = beg;
    for (; e + 7 < end; e += 8) {
        uint2 p[4];
        #pragma unroll
        for (int j = 0; j < 4; ++j) p[j] = s_edge[e + 2 * j + half];
        uint4 v[4];
        #pragma unroll
        for (int j = 0; j < 4; ++j) v[j] = hv[(size_t)p[j].x * 32 + l2];
        #pragma unroll
        for (int j = 0; j < 4; ++j) {
            float w = __uint_as_float(p[j].y);
            unsigned u[4] = {v[j].x, v[j].y, v[j].z, v[j].w};
            #pragma unroll
            for (int k = 0; k < 4; ++k) {
                acc[2 * k]     += w * bf2f(u[k] & 0xffffu);
                acc[2 * k + 1] += w * bf2f(u[k] >> 16);
            }
        }
    }
    for (; e + 1 < end; e += 2) {
        uint2 p = s_edge[e + half];
        uint4 v = hv[(size_t)p.x * 32 + l2];
        float w = __uint_as_float(p.y);
        unsigned u[4] = {v.x, v.y, v.z, v.w};
        #pragma unroll
        for (int k = 0; k < 4; ++k) {
            acc[2 * k]     += w * bf2f(u[k] & 0xffffu);
            acc[2 * k + 1] += w * bf2f(u[k] >> 16);
        }
    }
    if (half == 0 && e < end) {
        uint2 p = s_edge[e];
        uint4 v = hv[(size_t)p.x * 32 + l2];
        float w = __uint_as_float(p.y);
        unsigned u[4] = {v.x, v.y, v.z, v.w};
        #pragma unroll
        for (int k = 0; k < 4; ++k) {
            acc[2 * k]     += w * bf2f(u[k] & 0xffffu);
            acc[2 * k + 1] += w * bf2f(u[k] >> 16);
        }
    }
    #pragma unroll
    for (int k = 0; k < 8; ++k)
        acc[k] += __shfl_down(acc[k], 32, 64);
    if (half == 0) {
        uint4 o;
        o.x = (unsigned)f2bf(acc[0]) | ((unsigned)f2bf(acc[1]) << 16);
        o.y = (unsigned)f2bf(acc[2]) | ((unsigned)f2bf(acc[3]) << 16);
        o.z = (unsigned)f2bf(acc[4]) | ((unsigned)f2bf(acc[5]) << 16);
        o.w = (unsigned)f2bf(acc[6]) | ((unsigned)f2bf(acc[7]) << 16);
        ((uint4*)agg)[(size_t)node * 32 + l2] = o;
    }
}

// ---------------- aggregation (fp8, layer 0): 256 B rows, fp32 accumulate ----------

__device__ __forceinline__ void acc_fp8(float* acc, unsigned wx, unsigned wy, float w) {
    f32x2 a0 = __builtin_amdgcn_cvt_pk_f32_fp8(wx, false);
    f32x2 a1 = __builtin_amdgcn_cvt_pk_f32_fp8(wx, true);
    f32x2 a2 = __builtin_amdgcn_cvt_pk_f32_fp8(wy, false);
    f32x2 a3 = __builtin_amdgcn_cvt_pk_f32_fp8(wy, true);
    acc[0] += w * a0.x; acc[1] += w * a0.y;
    acc[2] += w * a1.x; acc[3] += w * a1.y;
    acc[4] += w * a2.x; acc[5] += w * a2.y;
    acc[6] += w * a3.x; acc[7] += w * a3.y;
}

__global__ __launch_bounds__(256) void k_agg_fp8(const unsigned* __restrict__ h8,
                                                 const int* __restrict__ row_beg,
                                                 const int* __restrict__ row_end,
                                                 const uint2* __restrict__ s_edge,
                                                 bfu* __restrict__ agg, int Nn) {
    int node = (int)((blockIdx.x * blockDim.x + threadIdx.x) >> 6);
    int lane = threadIdx.x & 63;
    if (node >= Nn) return;
    int half = lane >> 5;
    int l2 = lane & 31;
    int beg = row_beg[node], end = row_end[node];
    const uint2* hv = (const uint2*)h8;   // row = 32 uint2 = 256 B
    float acc[8];
    #pragma unroll
    for (int k = 0; k < 8; ++k) acc[k] = 0.f;
    int e = beg;
    for (; e + 7 < end; e += 8) {
        uint2 p[4];
        #pragma unroll
        for (int j = 0; j < 4; ++j) p[j] = s_edge[e + 2 * j + half];
        uint2 v[4];
        #pragma unroll
        for (int j = 0; j < 4; ++j) v[j] = hv[(size_t)p[j].x * 32 + l2];
        #pragma unroll
        for (int j = 0; j < 4; ++j)
            acc_fp8(acc, v[j].x, v[j].y, __uint_as_float(p[j].y));
    }
    for (; e + 1 < end; e += 2) {
        uint2 p = s_edge[e + half];
        uint2 v = hv[(size_t)p.x * 32 + l2];
        acc_fp8(acc, v.x, v.y, __uint_as_float(p.y));
    }
    if (half == 0 && e < end) {
        uint2 p = s_edge[e];
        uint2 v = hv[(size_t)p.x * 32 + l2];
        acc_fp8(acc, v.x, v.y, __uint_as_float(p.y));
    }
    #pragma unroll
    for (int k = 0; k < 8; ++k)
        acc[k] += __shfl_down(acc[k], 32, 64);
    if (half == 0) {
        uint4 o;
        o.x = (unsigned)f2bf(acc[0]) | ((unsigned)f2bf(acc[1]) << 16);
        o.y = (unsigned)f2bf(acc[2]) | ((unsigned)f2bf(acc[3]) << 16);
        o.z = (unsigned)f2bf(acc[4]) | ((unsigned)f2bf(acc[5]) << 16);
        o.w = (unsigned)f2bf(acc[6]) | ((unsigned)f2bf(acc[7]) << 16);
        ((uint4*)agg)[(size_t)node * 32 + l2] = o;
    }
}

// ---------------- bf16 MFMA GEMM: 64x64 tile, BK=64, XOR-swizzled LDS ----------------

__global__ __launch_bounds__(256) void gemm_mfma(
    const bfu* __restrict__ A1, int lda1, int K1,
    const bfu* __restrict__ A2, int lda2, int K2,
    const bfu* __restrict__ Wc, const float* __restrict__ bias,
    bfu* __restrict__ out, float* __restrict__ stats, int M) {
    __shared__ bfu lds[8192];
    __shared__ float sstat[128];
    bfu* As = lds;
    bfu* Bs = lds + 4096;
    bfu* Ct = lds;
    const int KT = K1 + K2;
    int tid = threadIdx.x;
    int lane = tid & 63;
    int w = tid >> 6;
    int wm = (w >> 1) * 32;
    int wn = (w & 1) * 32;
    int bid = blockIdx.x;
    int xcd = bid & 7;
    int slot = bid >> 3;
    int row0 = ((slot >> 2) * 8 + xcd) * 64;
    int col0 = (slot & 3) * 64;

    if (tid < 128) sstat[tid] = 0.f;

    f32x4 acc[2][2];
    #pragma unroll
    for (int i = 0; i < 2; ++i)
        #pragma unroll
        for (int j = 0; j < 2; ++j) acc[i][j] = (f32x4)(0.f);

    int sr8 = lane >> 3;
    int sslot = lane & 7;
    int rsel = lane & 15;
    int kg = lane >> 4;

    for (int k0 = 0; k0 < KT; k0 += 64) {
        const bfu* A; int lda, kk;
        if (k0 < K1) { A = A1; lda = lda1; kk = k0; }
        else         { A = A2; lda = lda2; kk = k0 - K1; }
        __syncthreads();
        #pragma unroll
        for (int t = 0; t < 2; ++t) {
            int r = w * 16 + t * 8 + sr8;
            int g = (sslot - r) & 7;
            GLOBAL_LOAD_LDS16(A + (size_t)(row0 + r) * lda + kk + g * 8,
                              As + (w * 16 + t * 8) * 64);
        }
        #pragma unroll
        for (int t = 0; t < 2; ++t) {
            int r = w * 16 + t * 8 + sr8;
            int g = (sslot - r) & 7;
            GLOBAL_LOAD_LDS16(Wc + (size_t)(col0 + r) * KT + k0 + g * 8,
                              Bs + (w * 16 + t * 8) * 64);
        }
        __syncthreads();

        bf16x8 af[2][2], bfr[2][2];
        #pragma unroll
        for (int ks = 0; ks < 2; ++ks) {
            #pragma unroll
            for (int i = 0; i < 2; ++i) {
                int rr = wm + i * 16 + rsel;
                int cc = ks * 4 + kg;
                af[ks][i] = *(const bf16x8*)&As[rr * 64 + (((cc + rr) & 7) << 3)];
            }
            #pragma unroll
            for (int j = 0; j < 2; ++j) {
                int nn = wn + j * 16 + rsel;
                int cc = ks * 4 + kg;
                bfr[ks][j] = *(const bf16x8*)&Bs[nn * 64 + (((cc + nn) & 7) << 3)];
            }
        }
        #pragma unroll
        for (int ks = 0; ks < 2; ++ks)
            #pragma unroll
            for (int i = 0; i < 2; ++i)
                #pragma unroll
                for (int j = 0; j < 2; ++j)
                    acc[i][j] = __builtin_amdgcn_mfma_f32_16x16x32_bf16(
                        af[ks][i], bfr[ks][j], acc[i][j], 0, 0, 0);
    }

    __syncthreads();

    int lgrp = lane >> 4;
    #pragma unroll
    for (int j = 0; j < 2; ++j) {
        int ccol = wn + j * 16 + rsel;
        float bv = bias[col0 + ccol];
        float s = 0.f, s2 = 0.f;
        #pragma unroll
        for (int i = 0; i < 2; ++i) {
            int rrb = wm + i * 16 + lgrp * 4;
            #pragma unroll
            for (int r = 0; r < 4; ++r) {
                int rr = rrb + r;
                float v = acc[i][j][r] + bv;
                Ct[rr * 72 + ccol] = f2bf(v);
                if (row0 + rr < M) { s += v; s2 += v * v; }
            }
        }
        s  += __shfl_xor(s, 16, 64);  s  += __shfl_xor(s, 32, 64);
        s2 += __shfl_xor(s2, 16, 64); s2 += __shfl_xor(s2, 32, 64);
        if (lgrp == 0) {
            atomicAdd(&sstat[ccol], s);
            atomicAdd(&sstat[64 + ccol], s2);
        }
    }
    __syncthreads();

    if (tid < 128) {
        int c = tid & 63;
        float v = sstat[tid];
        if (tid < 64) atomicAdd(&stats[col0 + c], v);
        else          atomicAdd(&stats[D + col0 + c], v);
    }

    int r = tid >> 2, cq = (tid & 3) * 16;
    if (row0 + r < M) {
        uint4 a = *(const uint4*)&Ct[r * 72 + cq];
        uint4 b = *(const uint4*)&Ct[r * 72 + cq + 8];
        uint4* gp = (uint4*)&out[(size_t)(row0 + r) * D + col0 + cq];
        gp[0] = a;
        gp[1] = b;
    }
}

// ---------------- BN apply: bf16 in -> bf16 h (+ optional fp8 h8) ----------------

__global__ __launch_bounds__(256) void bn_prelu_bf16(const bfu* __restrict__ hf,
                                                     const float* __restrict__ stats,
                                                     const float* __restrict__ g,
                                                     const float* __restrict__ be,
                                                     const float* __restrict__ a_ptr,
                                                     bfu* __restrict__ hb,
                                                     unsigned* __restrict__ h8,
                                                     int total4, int Nrows) {
    int idx = blockIdx.x * 256 + threadIdx.x;
    if (idx >= total4) return;
    float a = a_ptr[0];
    float inv = 1.0f / (float)Nrows;
    int c4 = (idx & 63) * 4;
    uint2 v = ((const uint2*)hf)[idx];
    float vin[4] = {bf2f(v.x & 0xffffu), bf2f(v.x >> 16),
                    bf2f(v.y & 0xffffu), bf2f(v.y >> 16)};
    float uo[4];
    bfu o[4];
    #pragma unroll
    for (int t = 0; t < 4; ++t) {
        int c = c4 + t;
        float m = stats[c] * inv;
        float var = stats[D + c] * inv - m * m;
        float sc = rsqrtf(var + EPS) * g[c];
        float sh = be[c] - m * sc;
        float u = vin[t] * sc + sh;
        u = u >= 0.f ? u : a * u;
        uo[t] = u;
        o[t] = f2bf(u);
    }
    uint2 ov;
    ov.x = (unsigned)o[0] | ((unsigned)o[1] << 16);
    ov.y = (unsigned)o[2] | ((unsigned)o[3] << 16);
    ((uint2*)hb)[idx] = ov;
    if (h8) {
        unsigned p8 = 0;
        p8 = __builtin_amdgcn_cvt_pk_fp8_f32(uo[0], uo[1], p8, false);
        p8 = __builtin_amdgcn_cvt_pk_fp8_f32(uo[2], uo[3], p8, true);
        h8[idx] = p8;
    }
}

// ---------------- fused post-BN + PReLU + head dot ----------------

__global__ __launch_bounds__(256) void k_final_fused(
    const float* __restrict__ x, const bfu* __restrict__ outf,
    const float* __restrict__ stats, const float* __restrict__ g,
    const float* __restrict__ be, const float* __restrict__ a_ptr,
    const float* __restrict__ Wf, const float* __restrict__ bf_,
    float* __restrict__ z, int Nn, int Nrows) {
    int node = (int)((blockIdx.x * blockDim.x + threadIdx.x) >> 6);
    int lane = threadIdx.x & 63;
    if (node >= Nn) return;
    float a = a_ptr[0];
    float inv = 1.0f / (float)Nrows;
    float s = x[(size_t)node * F_IN + lane] * Wf[lane]
            + x[(size_t)node * F_IN + 64 + lane] * Wf[64 + lane];
    uint2 v  = ((const uint2*)outf)[(size_t)node * 64 + lane];
    float4 wv = ((const float4*)(Wf + F_IN))[lane];
    float4 st1 = ((const float4*)stats)[lane];
    float4 st2 = ((const float4*)(stats + D))[lane];
    float4 gv = ((const float4*)g)[lane];
    float4 bev = ((const float4*)be)[lane];
    float vin[4] = {bf2f(v.x & 0xffffu), bf2f(v.x >> 16),
                    bf2f(v.y & 0xffffu), bf2f(v.y >> 16)};
    float m1[4] = {st1.x, st1.y, st1.z, st1.w};
    float m2[4] = {st2.x, st2.y, st2.z, st2.w};
    float gg[4] = {gv.x, gv.y, gv.z, gv.w};
    float bb[4] = {bev.x, bev.y, bev.z, bev.w};
    float ww[4] = {wv.x, wv.y, wv.z, wv.w};
    #pragma unroll
    for (int t = 0; t < 4; ++t) {
        float m = m1[t] * inv;
        float var = m2[t] * inv - m * m;
        float sc = rsqrtf(var + EPS) * gg[t];
        float sh = bb[t] - m * sc;
        float u = vin[t] * sc + sh;
        u = u >= 0.f ? u : a * u;
        s += u * ww[t];
    }
    #pragma unroll
    for (int off = 32; off; off >>= 1) s += __shfl_down(s, off, 64);
    if (lane == 0) z[node] = s + bf_[0];
}

__global__ __launch_bounds__(256) void k_zstats(const float* __restrict__ z,
                                                float* __restrict__ zs, int n) {
    float s = 0.f, s2 = 0.f;
    for (int i = blockIdx.x * blockDim.x + threadIdx.x; i < n; i += gridDim.x * blockDim.x) {
        float v = z[i];
        s += v; s2 += v * v;
    }
    #pragma unroll
    for (int off = 32; off; off >>= 1) {
        s += __shfl_down(s, off, 64);
        s2 += __shfl_down(s2, off, 64);
    }
    __shared__ float ws[4], ws2[4];
    int lane = threadIdx.x & 63, wid = threadIdx.x >> 6;
    if (lane == 0) { ws[wid] = s; ws2[wid] = s2; }
    __syncthreads();
    if (threadIdx.x == 0) {
        atomicAdd(&zs[0], ws[0] + ws[1] + ws[2] + ws[3]);
        atomicAdd(&zs[1], ws2[0] + ws2[1] + ws2[2] + ws2[3]);
    }
}

__global__ __launch_bounds__(256) void k_logsm(const float* __restrict__ z,
                                               const float* __restrict__ zs,
                                               const float* __restrict__ g,
                                               const float* __restrict__ be,
                                               const float* __restrict__ a_ptr,
                                               float* __restrict__ out, int C, int Ntot) {
    __shared__ float red[4], red2[4];
    int t = threadIdx.x;
    int lane = t & 63, wid = t >> 6;
    float mean = zs[0] / (float)Ntot;
    float var = zs[1] / (float)Ntot - mean * mean;
    float sc = rsqrtf(var + EPS) * g[0];
    float sh = be[0] - mean * sc;
    float a = a_ptr[0];
    const float* zg = z + (size_t)blockIdx.x * C;
    float vals[4];
    int cnt = 0;
    float mx = -3.4e38f;
    for (int i = t; i < C; i += 256) {
        float u = zg[i] * sc + sh;
        u = u >= 0.f ? u : a * u;
        vals[cnt++] = u;
        mx = fmaxf(mx, u);
    }
    #pragma unroll
    for (int off = 32; off; off >>= 1) mx = fmaxf(mx, __shfl_down(mx, off, 64));
    if (lane == 0) red[wid] = mx;
    __syncthreads();
    float M4 = fmaxf(fmaxf(red[0], red[1]), fmaxf(red[2], red[3]));
    float se = 0.f;
    for (int j = 0; j < cnt; ++j) se += expf(vals[j] - M4);
    #pragma unroll
    for (int off = 32; off; off >>= 1) se += __shfl_down(se, off, 64);
    if (lane == 0) red2[wid] = se;
    __syncthreads();
    float S4 = red2[0] + red2[1] + red2[2] + red2[3];
    float lse = logf(S4) + M4;
    cnt = 0;
    for (int i = t; i < C; i += 256) out[(size_t)blockIdx.x * C + i] = vals[cnt++] - lse;
}

// ---------------- launch ----------------

extern "C" void kernel_launch(void* const* d_in, const int* in_sizes, int n_in,
                              void* d_out, int out_size, void* d_ws, size_t ws_size,
                              hipStream_t stream) {
    const float* x      = (const float*)d_in[0];
    const int*   eidx   = (const int*)d_in[1];
    const float* e_w    = (const float*)d_in[2];
    const float* W_pre  = (const float*)d_in[4];
    const float* b_pre  = (const float*)d_in[5];
    const float* g_pre  = (const float*)d_in[6];
    const float* be_pre = (const float*)d_in[7];
    const float* a_pre  = (const float*)d_in[8];
    const float* W_rel  = (const float*)d_in[9];
    const float* b_rel  = (const float*)d_in[10];
    const float* W_root = (const float*)d_in[11];
    const float* g_conv = (const float*)d_in[12];
    const float* be_conv= (const float*)d_in[13];
    const float* a_conv = (const float*)d_in[14];
    const float* W_post = (const float*)d_in[15];
    const float* b_post = (const float*)d_in[16];
    const float* g_post = (const float*)d_in[17];
    const float* be_post= (const float*)d_in[18];
    const float* a_post = (const float*)d_in[19];
    const float* W_fin  = (const float*)d_in[20];
    const float* b_fin  = (const float*)d_in[21];
    const float* g_fin  = (const float*)d_in[22];
    const float* be_fin = (const float*)d_in[23];
    const float* a_fin  = (const float*)d_in[24];

    const int N = in_sizes[0] / F_IN;   // 50000
    const int E = in_sizes[2];          // 800000
    const int L = in_sizes[14];         // 3
    const int Npad = ((N + 511) / 512) * 512;   // 50176
    const int NB = (N + 255) >> 8;      // node buckets (196)
    const int* e_src = eidx;
    const int* e_dst = eidx + E;

    uint8_t* wsp = (uint8_t*)d_ws;
    size_t used = 0;
    auto alloc = [&](size_t bytes) -> void* {
        void* p = wsp + used;
        used += (bytes + 255) & ~(size_t)255;
        return p;
    };
    bfu*   xb       = (bfu*)alloc((size_t)Npad * F_IN * 2);
    bfu*   hb0      = (bfu*)alloc((size_t)Npad * D * 2);
    bfu*   hb1      = (bfu*)alloc((size_t)Npad * D * 2);
    unsigned* h8    = (unsigned*)alloc((size_t)Npad * D);
    bfu*   aggb     = (bfu*)alloc((size_t)Npad * D * 2);
    bfu*   outb     = (bfu*)alloc((size_t)Npad * D * 2);
    bfu*   Wt_pre   = (bfu*)alloc((size_t)D * F_IN * 2);
    bfu*   Wt_conv  = (bfu*)alloc((size_t)L * D * 512 * 2);
    bfu*   Wt_post  = (bfu*)alloc((size_t)D * D * 2);
    float* z        = (float*)alloc((size_t)N * 4);
    float* statsall = (float*)alloc((size_t)(5 * 2 * D + 2) * 4);
    int*   bucket_cursor = (int*)alloc((size_t)NB * 4);
    int*   row_beg  = (int*)alloc((size_t)N * 4);
    int*   row_end  = (int*)alloc((size_t)N * 4);
    uint2* s_tmp    = (uint2*)alloc((size_t)NB * BSTRIDE * 8);
    uint2* s_edge   = (uint2*)alloc((size_t)NB * BSTRIDE * 8);
    if (used > ws_size) {
        fprintf(stderr, "kernel_launch: ws too small (%zu > %zu)\n", used, ws_size);
        return;
    }
    float* st_pre  = statsall;
    float* st_post = statsall + 4 * 2 * D;
    float* zstats  = statsall + 5 * 2 * D;

    hipMemsetAsync(bucket_cursor, 0, (size_t)NB * 4, stream);
    hipMemsetAsync(statsall, 0, (size_t)(5 * 2 * D + 2) * 4, stream);

    // front end: cvt + LDS-tiled transposes (one launch)
    const int total4 = N * (F_IN / 4);
    const int CVT_BLOCKS = (total4 + 255) / 256;
    k_front<<<CVT_BLOCKS + 128, 256, 0, stream>>>(
        x, W_pre, W_rel, W_root, W_post,
        xb, Wt_pre, Wt_conv, Wt_post, CVT_BLOCKS, total4);

    // edge binning into fixed bucket regions (no global scan)
    k_binA<<<(E + ACHUNK - 1) / ACHUNK, 256, 0, stream>>>(e_src, e_dst, e_w, E,
                                                          bucket_cursor, s_tmp);
    k_binB<<<NB, 256, 0, stream>>>(s_tmp, bucket_cursor, s_edge, row_beg, row_end, N);

    const int gemm_grid = (Npad / 64) * 4;
    const int bn_blocks = (N * (D / 4) + 255) / 256;
    const int wave_blocks = (N + 3) / 4;

    // preprocess (BN dual-writes bf16 + fp8 shadow for layer-0 gather)
    gemm_mfma<<<gemm_grid, 256, 0, stream>>>(xb, F_IN, F_IN, nullptr, 0, 0,
                                             Wt_pre, b_pre, outb, st_pre, N);
    bn_prelu_bf16<<<bn_blocks, 256, 0, stream>>>(outb, st_pre, g_pre, be_pre, a_pre,
                                                 hb0, h8, N * (D / 4), N);

    bfu* hc = hb0;
    bfu* hn = hb1;
    for (int l = 0; l < L; ++l) {
        float* st = statsall + (1 + l) * 2 * D;
        if (l == 0)
            k_agg_fp8<<<wave_blocks, 256, 0, stream>>>(h8, row_beg, row_end, s_edge,
                                                       aggb, N);
        else
            k_agg<<<wave_blocks, 256, 0, stream>>>(hc, row_beg, row_end, s_edge,
                                                   aggb, N);
        gemm_mfma<<<gemm_grid, 256, 0, stream>>>(aggb, D, D, hc, D, D,
                                                 Wt_conv + (size_t)l * D * 512,
                                                 b_rel + (size_t)l * D, outb, st, N);
        bn_prelu_bf16<<<bn_blocks, 256, 0, stream>>>(outb, st, g_conv + (size_t)l * D,
                                                     be_conv + (size_t)l * D, a_conv + l,
                                                     hn, nullptr, N * (D / 4), N);
        bfu* tmp = hc; hc = hn; hn = tmp;
    }

    // postprocess gemm (stats fused) -> fused BN+PReLU+head dot
    gemm_mfma<<<gemm_grid, 256, 0, stream>>>(hc, D, D, nullptr, 0, 0,
                                             Wt_post, b_post, outb, st_post, N);
    k_final_fused<<<wave_blocks, 256, 0, stream>>>(x, outb, st_post, g_post, be_post,
                                                   a_post, W_fin, b_fin, z, N, N);
    k_zstats<<<64, 256, 0, stream>>>(z, zstats, N);
    k_logsm<<<N / 1000, 256, 0, stream>>>(z, zstats, g_fin, be_fin, a_fin,
                                          (float*)d_out, 1000, N);
}